// Round 5
// baseline (32335.367 us; speedup 1.0000x reference)
//
#include <hip/hip_runtime.h>

// PQMatcher persistent-kernel, round 5.
// r1: acquire/release gbar -> L2-invalidate storm, 63.8ms.
// r3: relaxed-sc1 monotonic global barrier (PROVEN) -> 30.3ms; 5x 256-wide
//     barriers (256 serialized RMWs ~80ns = ~20us each) dominate.
// r2/r4: finer-grained sync topologies -> container failed (hang suspected).
// r5: keep r3's PROVEN protocol (monotonic counters, relaxed RMW + relaxed
//     poll + acquire backstop, syncthreads-drained), but:
//  - Remap S2 so wave w of block (s,bg) does batch b0+w, q in [4s,4s+4).
//    Then EVERY stage is bg-local -> 4 independent 64-block pipelines,
//    zero cross-bg coupling, no whole-chip convoy.
//  - Hierarchical bg barrier: 4 sub-counters (16 blocks each, own line)
//    + root (4 incs). Arrival serialization 256 -> 16 RMWs (~2us/barrier).
//  - Batched sc1 staging loads (regs then LDS: one exposed latency).
//  - Per-wave register-hoisted Vvec; nontemporal WUq/uq streams; v carried
//    in registers; nontemporal out stores.
// Stage map per step p (per bg, 64 blocks, s = bid&63):
//   S1: s<16: t = Wpf@up_p + Wv@v ; s>=16: gh = W_hh@v + b_hh
//   S2: s[b0+w][4s..4s+4) = sum_h tanh(t+WUq)*Vvec   (wave w = batch)
//   S3: softmax(s[b]) + chalf = a@uq   (b = b0+(s>>3), i-slice s&7)
//   S4: c_ = sig(Wg2f@[up|chalf]) * chalf            (j-slice s*16..+16)
//   S5: gi = W_ih@c_ + b_ih, GRU fused -> v, out[p]  (same slice)

#define NB 32
#define WOFF 16384  // ints reserved for sync counters at ws base

__device__ __forceinline__ float fsig(float x) { return 1.0f / (1.0f + __expf(-x)); }
__device__ __forceinline__ float ftanh(float x) { return 1.0f - 2.0f / (1.0f + __expf(2.0f * x)); }

__device__ __forceinline__ float wred(float a) {
#pragma unroll
  for (int o = 32; o >= 1; o >>= 1) a += __shfl_xor(a, o, 64);
  return a;
}

__device__ __forceinline__ float cload(const float* p) {
  return __hip_atomic_load(p, __ATOMIC_RELAXED, __HIP_MEMORY_SCOPE_AGENT);
}
__device__ __forceinline__ void cstore(float* p, float v) {
  __hip_atomic_store(p, v, __ATOMIC_RELAXED, __HIP_MEMORY_SCOPE_AGENT);
}
__device__ __forceinline__ int cloadi(const int* p) {
  return __hip_atomic_load(p, __ATOMIC_RELAXED, __HIP_MEMORY_SCOPE_AGENT);
}

// hierarchical bg-local barrier (64 blocks): 4 sub-lines x 16 arrivals + root.
// Monotonic counters; barrier #bar complete when root >= 4*bar. Same proven
// r3 protocol: relaxed RMW/poll, acquire load every 256 polls as backstop.
// __syncthreads() before the RMW drains vmcnt -> prior sc1 stores visible.
__device__ __forceinline__ void bgbar(int* sub, int* root, int bar) {
  __syncthreads();
  if (threadIdx.x == 0) {
    int old = __hip_atomic_fetch_add(sub, 1, __ATOMIC_RELAXED, __HIP_MEMORY_SCOPE_AGENT);
    if (old == 16 * bar - 1)
      __hip_atomic_fetch_add(root, 1, __ATOMIC_RELAXED, __HIP_MEMORY_SCOPE_AGENT);
    int tgt = 4 * bar, spins = 0;
    for (;;) {
      if (cloadi(root) >= tgt) break;
      __builtin_amdgcn_s_sleep(2);
      if (((++spins) & 255) == 0 &&
          __hip_atomic_load(root, __ATOMIC_ACQUIRE, __HIP_MEMORY_SCOPE_AGENT) >= tgt)
        break;
    }
  }
  __syncthreads();
}

// ---------------- init: counter zero + folds + v0 copy ----------------
__global__ __launch_bounds__(256) void k_init(
    const float* __restrict__ v0, const float* __restrict__ Wp,
    const float* __restrict__ Wg, float* __restrict__ wsbase,
    float* __restrict__ vbuf, float* __restrict__ Wpf, float* __restrict__ Wg2f) {
  int i = blockIdx.x * 256 + threadIdx.x;
  if (i < WOFF) ((int*)wsbase)[i] = 0;
  if (i < NB * 1024) vbuf[i] = v0[i];
  if (i < 1024 * 512) {
    int n = i >> 9, k = i & 511;
    Wpf[i] = Wp[(size_t)n * 1024 + k] + Wp[(size_t)n * 1024 + k + 512];
  }
  if (i < 1024 * 1024) {
    int j = i >> 10, kk = i & 1023;
    const float* wr = Wg + (size_t)(1024 + j) * 2048;
    // r = [up, up, c, c]: fold duplicated K-halves
    Wg2f[i] = (kk < 512) ? (wr[kk] + wr[kk + 512]) : (wr[kk + 512] + wr[kk + 1024]);
  }
}

// ---------------- WUq = uq @ Wqf.T : [8192,512] x [512,1024] ----------------
__global__ __launch_bounds__(256) void k_wuq(
    const float* __restrict__ A, const float* __restrict__ Wq, float* __restrict__ C) {
  __shared__ float As[16][65];
  __shared__ float Bs[16][65];
  int bm = blockIdx.x * 64, bn = blockIdx.y * 64;
  int t = threadIdx.x;
  int tx = t & 15, ty = t >> 4;
  float acc[4][4] = {};
  for (int k0 = 0; k0 < 512; k0 += 16) {
#pragma unroll
    for (int l = 0; l < 4; ++l) {
      int idx = t + l * 256;
      int row = idx >> 4, kk = idx & 15;
      As[kk][row] = A[(size_t)(bm + row) * 512 + k0 + kk];
      Bs[kk][row] = Wq[(size_t)(bn + row) * 1024 + k0 + kk] +
                    Wq[(size_t)(bn + row) * 1024 + k0 + kk + 512];
    }
    __syncthreads();
#pragma unroll
    for (int kk = 0; kk < 16; ++kk) {
      float a0[4], b0[4];
#pragma unroll
      for (int i = 0; i < 4; ++i) a0[i] = As[kk][ty * 4 + i];
#pragma unroll
      for (int j = 0; j < 4; ++j) b0[j] = Bs[kk][tx * 4 + j];
#pragma unroll
      for (int i = 0; i < 4; ++i)
#pragma unroll
        for (int j = 0; j < 4; ++j) acc[i][j] += a0[i] * b0[j];
    }
    __syncthreads();
  }
#pragma unroll
  for (int i = 0; i < 4; ++i)
#pragma unroll
    for (int j = 0; j < 4; ++j)
      C[(size_t)(bm + ty * 4 + i) * 1024 + bn + tx * 4 + j] = acc[i][j];
}

// ---------------- the persistent 256-step scan ----------------
__global__ __launch_bounds__(512, 2) void k_loop(
    const float* __restrict__ up, const float* __restrict__ uq,
    const float* __restrict__ Vvec, const float* __restrict__ Wv,
    const float* __restrict__ W_hh, const float* __restrict__ b_hh,
    const float* __restrict__ W_ih, const float* __restrict__ b_ih,
    float* __restrict__ out, float* __restrict__ ws) {
  int* cbase = (int*)ws;  // per bg: sub[4] at (bg*8+0..3)*64, root at (bg*8+4)*64

  float* vbuf  = ws + WOFF;            // [32][1024]
  float* tbuf  = ws + WOFF + 32768;    // [32][1024]
  float* ghbuf = ws + WOFF + 65536;    // [32][3072] (includes b_hh)
  float* sbuf  = ws + WOFF + 163840;   // [32][256]
  float* chalf = ws + WOFF + 172032;   // [32][512]
  float* cbuf  = ws + WOFF + 188416;   // [32][1024]
  float* Wpf   = ws + WOFF + 221184;   // [1024][512]
  float* Wg2f  = ws + WOFF + 745472;   // [1024][1024]
  float* WUq   = ws + WOFF + 1794048;  // [8192][1024]

  int bid = blockIdx.x;
  int tid = threadIdx.x, lane = tid & 63, wave = tid >> 6;

  __shared__ float smem[12288];  // 48KB

  int s = bid & 63, bg = bid >> 6, b0 = bg * 8;
  bool is_t = (s < 16);
  int b3 = b0 + (s >> 3), i0 = (s & 7) * 64;      // S3 mapping (bg-local)

  int* subc = cbase + (bg * 8 + (s >> 4)) * 64;
  int* rootc = cbase + (bg * 8 + 4) * 64;

  // loop-invariant Vvec fragment for S2: wave w owns batch b0+w
  float vvreg[16];
#pragma unroll
  for (int i = 0; i < 16; ++i)
    vvreg[i] = Vvec[(size_t)(b0 + wave) * 1024 + lane + i * 64];

  // v element owned by this thread (S5 tail): one (b,h) per tid<128
  int ho5 = tid >> 3, bb5 = tid & 7;
  int h5 = s * 16 + ho5, b5 = b0 + bb5;
  float vloc = 0.0f;
  if (tid < 128) vloc = cload(vbuf + (size_t)b5 * 1024 + h5);

  int bar = 0;

  for (int p = 0; p < 256; ++p) {
    // ================= S1: t = Wpf@up + Wv@v ; gh = W_hh@v + b_hh =========
    {
      float tmp[16];
#pragma unroll
      for (int i = 0; i < 16; ++i)
        tmp[i] = cload(vbuf + (size_t)b0 * 1024 + tid + i * 512);
#pragma unroll
      for (int i = 0; i < 16; ++i) smem[tid + i * 512] = tmp[i];
      if (is_t) {
        float tu[8];
#pragma unroll
        for (int i = 0; i < 8; ++i)
          tu[i] = up[((size_t)p * NB + b0) * 512 + tid + i * 512];
#pragma unroll
        for (int i = 0; i < 8; ++i) smem[8192 + tid + i * 512] = tu[i];
      }
      __syncthreads();
      float vreg[8][16];
#pragma unroll
      for (int bb = 0; bb < 8; ++bb)
#pragma unroll
        for (int i = 0; i < 16; ++i)
          vreg[bb][i] = smem[bb * 1024 + lane + i * 64];
      int n0 = s * 64 + wave * 8;
      for (int rr = 0; rr < 8; ++rr) {
        int n = n0 + rr;
        float acc[8];
#pragma unroll
        for (int bb = 0; bb < 8; ++bb) acc[bb] = 0.0f;
        if (is_t) {
          const float* wr = Wv + (size_t)n * 1024;
#pragma unroll
          for (int i = 0; i < 16; ++i) {
            float w = wr[lane + i * 64];
#pragma unroll
            for (int bb = 0; bb < 8; ++bb) acc[bb] = fmaf(w, vreg[bb][i], acc[bb]);
          }
          const float* wp = Wpf + (size_t)n * 512;
#pragma unroll
          for (int i = 0; i < 8; ++i) {
            float w = wp[lane + i * 64];
#pragma unroll
            for (int bb = 0; bb < 8; ++bb)
              acc[bb] = fmaf(w, smem[8192 + bb * 512 + lane + i * 64], acc[bb]);
          }
#pragma unroll
          for (int bb = 0; bb < 8; ++bb) {
            float a = wred(acc[bb]);
            if (lane == 0) cstore(tbuf + (size_t)(b0 + bb) * 1024 + n, a);
          }
        } else {
          int m = n - 1024;
          const float* wr = W_hh + (size_t)m * 1024;
#pragma unroll
          for (int i = 0; i < 16; ++i) {
            float w = wr[lane + i * 64];
#pragma unroll
            for (int bb = 0; bb < 8; ++bb) acc[bb] = fmaf(w, vreg[bb][i], acc[bb]);
          }
          float bias = b_hh[m];
#pragma unroll
          for (int bb = 0; bb < 8; ++bb) {
            float a = wred(acc[bb]);
            if (lane == 0) cstore(ghbuf + (size_t)(b0 + bb) * 3072 + m, a + bias);
          }
        }
      }
    }
    ++bar; bgbar(subc, rootc, bar);

    // ================= S2: s[b0+w][4s..4s+4) = sum_h tanh(t+WUq)*Vvec ======
    {
      float tmp[16];
#pragma unroll
      for (int i = 0; i < 16; ++i)
        tmp[i] = cload(tbuf + (size_t)b0 * 1024 + tid + i * 512);
#pragma unroll
      for (int i = 0; i < 16; ++i) smem[tid + i * 512] = tmp[i];
      __syncthreads();
      float treg[16];
#pragma unroll
      for (int i = 0; i < 16; ++i) treg[i] = smem[wave * 1024 + lane + i * 64];
      int bq = b0 + wave;
      for (int qq = 0; qq < 4; ++qq) {
        int q = s * 4 + qq;
        const float* wu = WUq + ((size_t)q * NB + bq) * 1024;
        float a = 0.0f;
#pragma unroll
        for (int i = 0; i < 16; ++i)
          a += ftanh(treg[i] + __builtin_nontemporal_load(wu + lane + i * 64)) * vvreg[i];
        a = wred(a);
        if (lane == 0) cstore(sbuf + bq * 256 + q, a);
      }
    }
    ++bar; bgbar(subc, rootc, bar);

    // ================= S3: softmax (per-block redundant) + chalf = a@uq ====
    {
      float* a_s  = smem;         // 256
      float* red  = smem + 256;   // 8
      float* part = smem + 512;   // 512
      int b = b3;
      float sv = -1e30f;
      if (tid < 256) sv = cload(sbuf + b * 256 + tid);
      float m = sv;
#pragma unroll
      for (int o = 32; o >= 1; o >>= 1) m = fmaxf(m, __shfl_xor(m, o, 64));
      if (lane == 0 && wave < 4) red[wave] = m;
      __syncthreads();
      float bm = fmaxf(fmaxf(red[0], red[1]), fmaxf(red[2], red[3]));
      __syncthreads();
      float e = 0.0f;
      if (tid < 256) e = __expf(sv - bm);
      float se = e;
#pragma unroll
      for (int o = 32; o >= 1; o >>= 1) se += __shfl_xor(se, o, 64);
      if (lane == 0 && wave < 4) red[wave] = se;
      __syncthreads();
      float tot = red[0] + red[1] + red[2] + red[3];
      if (tid < 256) a_s[tid] = e / tot;
      __syncthreads();
      // chalf[b][i0+lane], wave w sums its 32 q's
      float acc = 0.0f;
      for (int qq = 0; qq < 32; ++qq) {
        int q = wave * 32 + qq;
        acc += a_s[q] *
               __builtin_nontemporal_load(uq + ((size_t)q * NB + b) * 512 + i0 + lane);
      }
      part[wave * 64 + lane] = acc;
      __syncthreads();
      if (tid < 64) {
        float c = 0.0f;
#pragma unroll
        for (int w = 0; w < 8; ++w) c += part[w * 64 + tid];
        cstore(chalf + (size_t)b * 512 + i0 + tid, c);
      }
    }
    ++bar; bgbar(subc, rootc, bar);

    // ================= S4: c_ = sig(Wg2f@[up|chalf]) * chalf ===============
    {
      float tc[8];
#pragma unroll
      for (int i = 0; i < 8; ++i)
        tc[i] = cload(chalf + (size_t)b0 * 512 + tid + i * 512);
#pragma unroll
      for (int i = 0; i < 8; ++i) smem[tid + i * 512] = tc[i];
      __syncthreads();
      float rreg[8][16];
#pragma unroll
      for (int bb = 0; bb < 8; ++bb) {
#pragma unroll
        for (int i = 0; i < 8; ++i)
          rreg[bb][i] = up[((size_t)p * NB + b0 + bb) * 512 + lane + i * 64];
#pragma unroll
        for (int i = 0; i < 8; ++i)
          rreg[bb][8 + i] = smem[bb * 512 + lane + i * 64];
      }
      int j0 = s * 16 + wave * 2;
      for (int rr = 0; rr < 2; ++rr) {
        int j = j0 + rr;
        const float* wr = Wg2f + (size_t)j * 1024;
        float acc[8];
#pragma unroll
        for (int bb = 0; bb < 8; ++bb) acc[bb] = 0.0f;
#pragma unroll
        for (int i = 0; i < 16; ++i) {
          float w = wr[lane + i * 64];
#pragma unroll
          for (int bb = 0; bb < 8; ++bb) acc[bb] = fmaf(w, rreg[bb][i], acc[bb]);
        }
#pragma unroll
        for (int bb = 0; bb < 8; ++bb) {
          float a = wred(acc[bb]);
          if (lane == 0) {
            float cv = smem[bb * 512 + (j & 511)];
            cstore(cbuf + (size_t)(b0 + bb) * 1024 + j, fsig(a) * cv);
          }
        }
      }
    }
    ++bar; bgbar(subc, rootc, bar);

    // ================= S5: gi = W_ih@c_ + b_ih, GRU fused -> v, out[p] =====
    {
      float ghr = 0.0f, ghz = 0.0f, ghn = 0.0f;
      if (tid < 128) {
        const float* ghb = ghbuf + (size_t)b5 * 3072;
        ghr = cload(ghb + h5);
        ghz = cload(ghb + 1024 + h5);
        ghn = cload(ghb + 2048 + h5);
      }
      float tmp[16];
#pragma unroll
      for (int i = 0; i < 16; ++i)
        tmp[i] = cload(cbuf + (size_t)b0 * 1024 + tid + i * 512);
#pragma unroll
      for (int i = 0; i < 16; ++i) smem[tid + i * 512] = tmp[i];
      __syncthreads();
      float creg[8][16];
#pragma unroll
      for (int bb = 0; bb < 8; ++bb)
#pragma unroll
        for (int i = 0; i < 16; ++i)
          creg[bb][i] = smem[bb * 1024 + lane + i * 64];
      float* gi_s = smem + 8192;  // [48][8] = (g*16+ho)*8 + bb
      for (int k = 0; k < 6; ++k) {
        int idx = wave * 6 + k;          // 0..47
        int g = idx >> 4, ho = idx & 15;
        int r = g * 1024 + s * 16 + ho;
        const float* wr = W_ih + (size_t)r * 1024;
        float acc[8];
#pragma unroll
        for (int bb = 0; bb < 8; ++bb) acc[bb] = 0.0f;
#pragma unroll
        for (int i = 0; i < 16; ++i) {
          float w = wr[lane + i * 64];
#pragma unroll
          for (int bb = 0; bb < 8; ++bb) acc[bb] = fmaf(w, creg[bb][i], acc[bb]);
        }
        float bias = b_ih[r];
#pragma unroll
        for (int bb = 0; bb < 8; ++bb) {
          float a = wred(acc[bb]);
          if (lane == 0) gi_s[idx * 8 + bb] = a + bias;
        }
      }
      __syncthreads();
      if (tid < 128) {
        float gir = gi_s[(0 * 16 + ho5) * 8 + bb5];
        float giz = gi_s[(1 * 16 + ho5) * 8 + bb5];
        float gin = gi_s[(2 * 16 + ho5) * 8 + bb5];
        float rg = fsig(gir + ghr);
        float z  = fsig(giz + ghz);
        float nn = ftanh(gin + rg * ghn);
        float vn = (1.0f - z) * nn + z * vloc;
        vloc = vn;
        cstore(vbuf + (size_t)b5 * 1024 + h5, vn);
        __builtin_nontemporal_store(vn, out + ((size_t)p * NB + b5) * 1024 + h5);
      }
    }
    ++bar; bgbar(subc, rootc, bar);
  }
}

extern "C" void kernel_launch(void* const* d_in, const int* in_sizes, int n_in,
                              void* d_out, int out_size, void* d_ws, size_t ws_size,
                              hipStream_t stream) {
  const float* up = (const float*)d_in[0];
  const float* uq = (const float*)d_in[1];
  const float* v0 = (const float*)d_in[2];
  const float* Vvec = (const float*)d_in[3];
  const float* Wp = (const float*)d_in[4];
  const float* Wq = (const float*)d_in[5];
  const float* Wv = (const float*)d_in[6];
  const float* Wg = (const float*)d_in[7];
  const float* W_ih = (const float*)d_in[8];
  const float* W_hh = (const float*)d_in[9];
  const float* b_ih = (const float*)d_in[10];
  const float* b_hh = (const float*)d_in[11];
  float* out = (float*)d_out;
  float* ws = (float*)d_ws;

  float* vbuf = ws + WOFF;
  float* Wpf  = ws + WOFF + 221184;
  float* Wg2f = ws + WOFF + 745472;
  float* WUq  = ws + WOFF + 1794048;

  k_init<<<4096, 256, 0, stream>>>(v0, Wp, Wg, ws, vbuf, Wpf, Wg2f);
  k_wuq<<<dim3(128, 16), 256, 0, stream>>>(uq, Wq, WUq);
  // 256 blocks x 512 threads, <=256 VGPR, 48KB LDS -> 1 block/CU, all 256
  // blocks co-resident -> bg-local spin barriers are safe.
  k_loop<<<256, 512, 0, stream>>>(up, uq, Vvec, Wv, W_hh, b_hh, W_ih, b_ih, out, ws);
}